// Round 4
// baseline (162.204 us; speedup 1.0000x reference)
//
#include <hip/hip_runtime.h>
#include <stdint.h>

#define D_MODEL 1024
#define T_LEN   4096
#define B_SZ    4
#define NROWS   (B_SZ * T_LEN)   // 16384
#define NPROJ   (2 * D_MODEL)    // 2048
#define CHUNK   16               // rows of T per k_post block

#define BM 256
#define BN 256
#define BK2 32
#define NT2 (D_MODEL / BK2)      // 32 K-steps
#define NBUF 4

typedef __attribute__((ext_vector_type(8))) __bf16 bf16x8;
typedef __attribute__((ext_vector_type(4))) float  f32x4;

using as1_void = __attribute__((address_space(1))) void;
using as3_void = __attribute__((address_space(3))) void;

__device__ inline float bf2f(unsigned short u) {
    union { unsigned int i; float f; } v; v.i = ((unsigned int)u) << 16; return v.f;
}
__device__ inline unsigned short f2bf(float f) {
    union { float f; unsigned int i; } v; v.f = f;
    return (unsigned short)((v.i + 0x7fffu + ((v.i >> 16) & 1u)) >> 16);
}
__device__ inline float sigmoidf(float x) { return 1.0f / (1.0f + __expf(-x)); }

// ---------------- K0a: x fp32 -> bf16 ----------------
__global__ __launch_bounds__(256) void k_cvt_x(const float* __restrict__ x,
                                               unsigned short* __restrict__ xb) {
    int i = (blockIdx.x * 256 + threadIdx.x) * 4;
    float4 v = *reinterpret_cast<const float4*>(x + i);
    ushort4 o;
    o.x = f2bf(v.x); o.y = f2bf(v.y); o.z = f2bf(v.z); o.w = f2bf(v.w);
    *reinterpret_cast<ushort4*>(xb + i) = o;
}

// ---------------- K0b: W (1024x2048) -> W^T (2048x1024) bf16 ----------------
__global__ __launch_bounds__(256) void k_cvt_w(const float* __restrict__ W,
                                               unsigned short* __restrict__ wt) {
    __shared__ unsigned short tile[32][33];
    int n0 = blockIdx.x * 32, k0 = blockIdx.y * 32;
    int c = threadIdx.x & 31, r = threadIdx.x >> 5;  // r in 0..7
    #pragma unroll
    for (int i = 0; i < 4; i++) {
        int kk = r + i * 8;
        tile[kk][c] = f2bf(W[(uint64_t)(k0 + kk) * NPROJ + n0 + c]);
    }
    __syncthreads();
    #pragma unroll
    for (int i = 0; i < 4; i++) {
        int nn = r + i * 8;
        wt[(uint64_t)(n0 + nn) * D_MODEL + k0 + c] = tile[c][nn];
    }
}

// ---------------- K1: GEMM proj = xb @ wt^T + bias, store bf16 ----------------
// 256x256 tile, BK=32, 8 waves (2Mx4N), FOUR LDS buffers (128 KiB),
// depth-3 prefetch with counted vmcnt(8) -- loads never drain to 0 in the
// main loop (T4). Raw s_barrier (no vmcnt(0) drain) + sched_barrier fence.
// T2 xor-swizzle (inverse on global source, same involution on ds_read).
// T1 XCD-aware block swizzle (512 blocks, bijective).
__global__ __launch_bounds__(512, 2) void k_gemm(const unsigned short* __restrict__ xb,
                                                 const unsigned short* __restrict__ wt,
                                                 const float* __restrict__ bias,
                                                 unsigned short* __restrict__ projb) {
    __shared__ __align__(16) unsigned short As[NBUF * BM * BK2];  // 64 KB
    __shared__ __align__(16) unsigned short Bs[NBUF * BM * BK2];  // 64 KB

    const int tid  = threadIdx.x;
    const int lane = tid & 63;
    const int w    = tid >> 6;       // wave 0..7
    const int wm   = w >> 2;         // 0..1  (M half)
    const int wn   = w & 3;          // 0..3  (N quarter)

    // T1: 512 blocks = 8 n-tiles x 64 m-tiles; XCD k owns n-column k.
    const int bid = blockIdx.x;
    const int wg  = (bid & 7) * 64 + (bid >> 3);
    const int n0  = (wg >> 6) * BN;
    const int m0  = (wg & 63) * BM;

    // staging: per tile, A = 256x32 bf16 = 16KB = 2 issues of (512thr x 16B);
    // issue i covers rows i*128..i*128+127. row = tid>>2, col-octet = tid&3.
    const int srow = tid >> 2;              // 0..127
    const int skey = (tid >> 3) & 3;        // == (globalrow>>1)&3
    const int scol = ((tid & 3) ^ skey) * 8;  // T2 inverse-swizzled source octet
    const int fr   = lane & 15;
    const int fq   = lane >> 4;

    f32x4 acc[8][4] = {};

    auto STAGE = [&](int tk) {
        const int buf = tk & 3;
        const int ks  = tk * BK2;
        #pragma unroll
        for (int i = 0; i < 2; ++i) {
            const unsigned short* ga = xb + (uint64_t)(m0 + i * 128 + srow) * D_MODEL + ks + scol;
            __builtin_amdgcn_global_load_lds((as1_void*)(void*)ga,
                (as3_void*)(void*)&As[buf * 8192 + i * 4096 + w * 512], 16, 0, 0);
        }
        #pragma unroll
        for (int i = 0; i < 2; ++i) {
            const unsigned short* gb = wt + (uint64_t)(n0 + i * 128 + srow) * D_MODEL + ks + scol;
            __builtin_amdgcn_global_load_lds((as1_void*)(void*)gb,
                (as3_void*)(void*)&Bs[buf * 8192 + i * 4096 + w * 512], 16, 0, 0);
        }
    };

    // prologue: fill pipeline 3 deep; wait only for tile 0 (8 = tiles 1,2 in flight)
    STAGE(0); STAGE(1); STAGE(2);
    asm volatile("s_waitcnt vmcnt(8)" ::: "memory");
    __builtin_amdgcn_s_barrier();
    __builtin_amdgcn_sched_barrier(0);

    for (int t = 0; t < NT2; ++t) {
        if (t + 3 < NT2) STAGE(t + 3);   // issue-first; lands by vmcnt 3 steps later

        const unsigned short* Ab = &As[(t & 3) * 8192];
        const unsigned short* Bb = &Bs[(t & 3) * 8192];
        bf16x8 a[8], b[4];
        #pragma unroll
        for (int n = 0; n < 4; n++) {
            const int rb = wn * 64 + n * 16 + fr;
            b[n] = *reinterpret_cast<const bf16x8*>(&Bb[rb * 32 + ((fq ^ ((rb >> 1) & 3)) * 8)]);
        }
        #pragma unroll
        for (int m = 0; m < 8; m++) {
            const int ra = wm * 128 + m * 16 + fr;
            a[m] = *reinterpret_cast<const bf16x8*>(&Ab[ra * 32 + ((fq ^ ((ra >> 1) & 3)) * 8)]);
        }
        #pragma unroll
        for (int m = 0; m < 8; m++)
            #pragma unroll
            for (int n = 0; n < 4; n++)
                acc[m][n] = __builtin_amdgcn_mfma_f32_16x16x32_bf16(a[m], b[n], acc[m][n], 0, 0, 0);

        if (t < NT2 - 1) {
            // counted wait: tile t+1 landed; tiles t+2,t+3 stay in flight
            if (t + 3 < NT2)      asm volatile("s_waitcnt vmcnt(8)" ::: "memory");
            else if (t + 2 < NT2) asm volatile("s_waitcnt vmcnt(4)" ::: "memory");
            else                  asm volatile("s_waitcnt vmcnt(0)" ::: "memory");
            __builtin_amdgcn_s_barrier();
            __builtin_amdgcn_sched_barrier(0);
        }
    }

    // epilogue: D layout col=lane&15, row=(lane>>4)*4+reg  [verified m89/m91]
    #pragma unroll
    for (int m = 0; m < 8; m++) {
        const int grow = m0 + wm * 128 + m * 16 + fq * 4;
        #pragma unroll
        for (int n = 0; n < 4; n++) {
            const int gcol = n0 + wn * 64 + n * 16 + fr;
            const float bv = bias[gcol];
            #pragma unroll
            for (int r = 0; r < 4; r++) {
                projb[(uint64_t)(grow + r) * NPROJ + gcol] = f2bf(acc[m][n][r] + bv);
            }
        }
    }
}

// ---------------- K2: streaming RoPE + conv7 + SiLU + gate + RMSNorm ----------------
__global__ __launch_bounds__(512) void k_post(const unsigned short* __restrict__ projb,
                                              const float* __restrict__ sinp,
                                              const float* __restrict__ cosp,
                                              const float* __restrict__ kw,
                                              const float* __restrict__ dwb,
                                              const float* __restrict__ gamma,
                                              float* __restrict__ out) {
    const int blk  = blockIdx.x;
    const int b    = blk / (T_LEN / CHUNK);
    const int t0   = (blk % (T_LEN / CHUNK)) * CHUNK;
    const int c    = threadIdx.x;          // pair index 0..511
    const int d0   = c * 2;
    const uint64_t bbase = (uint64_t)b * T_LEN;

    float kwv[7][2];
    #pragma unroll
    for (int j = 0; j < 7; j++) {
        kwv[j][0] = kw[j * D_MODEL + d0];
        kwv[j][1] = kw[j * D_MODEL + d0 + 1];
    }
    const float bv0 = dwb[d0], bv1 = dwb[d0 + 1];
    const float gm0 = gamma[d0], gm1 = gamma[d0 + 1];

    __shared__ float red[2][8];

    auto load_rope = [&](int tj, float& o0, float& o1) {
        if ((unsigned)tj < (unsigned)T_LEN) {
            ushort2 u = *reinterpret_cast<const ushort2*>(projb + (bbase + tj) * NPROJ + d0);
            float cv = cosp[(uint64_t)tj * (D_MODEL / 2) + c];
            float sv = sinp[(uint64_t)tj * (D_MODEL / 2) + c];
            float x0 = bf2f(u.x), x1 = bf2f(u.y);
            o0 = x0 * cv - x1 * sv;
            o1 = x0 * sv + x1 * cv;
        } else { o0 = 0.f; o1 = 0.f; }
    };

    float rg[6][2];
    #pragma unroll
    for (int j = 0; j < 6; j++) load_rope(t0 - 3 + j, rg[j][0], rg[j][1]);
    float nx0, nx1;
    load_rope(t0 + 3, nx0, nx1);

    ushort2 xb_cur = *reinterpret_cast<const ushort2*>(projb + (bbase + t0) * NPROJ + D_MODEL + d0);

    for (int t = t0; t < t0 + CHUNK; ++t) {
        const float r60 = nx0, r61 = nx1;

        float acc0 = rg[0][0] * kwv[0][0] + rg[1][0] * kwv[1][0] + rg[2][0] * kwv[2][0]
                   + rg[3][0] * kwv[3][0] + rg[4][0] * kwv[4][0] + rg[5][0] * kwv[5][0]
                   + r60 * kwv[6][0] + bv0;
        float acc1 = rg[0][1] * kwv[0][1] + rg[1][1] * kwv[1][1] + rg[2][1] * kwv[2][1]
                   + rg[3][1] * kwv[3][1] + rg[4][1] * kwv[4][1] + rg[5][1] * kwv[5][1]
                   + r61 * kwv[6][1] + bv1;

        load_rope(t + 4, nx0, nx1);
        const ushort2 xb_use = xb_cur;
        if (t + 1 < t0 + CHUNK) {
            xb_cur = *reinterpret_cast<const ushort2*>(projb + (bbase + t + 1) * NPROJ + D_MODEL + d0);
        }

        float a0 = acc0 * sigmoidf(acc0);
        float a1 = acc1 * sigmoidf(acc1);
        float g0 = a0 * sigmoidf(bf2f(xb_use.x));
        float g1 = a1 * sigmoidf(bf2f(xb_use.y));

        float ssq = g0 * g0 + g1 * g1;
        #pragma unroll
        for (int off = 32; off; off >>= 1) ssq += __shfl_down(ssq, off);
        const int p = t & 1;
        if ((threadIdx.x & 63) == 0) red[p][threadIdx.x >> 6] = ssq;
        __syncthreads();
        float total = red[p][0] + red[p][1] + red[p][2] + red[p][3]
                    + red[p][4] + red[p][5] + red[p][6] + red[p][7];
        const float inv = 1.0f / sqrtf(total * (1.0f / (float)D_MODEL) + 1e-8f);

        float2 o;
        o.x = g0 * inv * gm0;
        o.y = g1 * inv * gm1;
        *reinterpret_cast<float2*>(out + (bbase + t) * D_MODEL + d0) = o;

        #pragma unroll
        for (int j = 0; j < 5; j++) { rg[j][0] = rg[j + 1][0]; rg[j][1] = rg[j + 1][1]; }
        rg[5][0] = r60; rg[5][1] = r61;
    }
}

extern "C" void kernel_launch(void* const* d_in, const int* in_sizes, int n_in,
                              void* d_out, int out_size, void* d_ws, size_t ws_size,
                              hipStream_t stream) {
    const float* x     = (const float*)d_in[0];
    const float* sinp  = (const float*)d_in[1];
    const float* cosp  = (const float*)d_in[2];
    const float* W     = (const float*)d_in[3];
    const float* bproj = (const float*)d_in[4];
    const float* dwk   = (const float*)d_in[5];
    const float* dwb   = (const float*)d_in[6];
    const float* gamma = (const float*)d_in[7];
    float* out = (float*)d_out;

    unsigned short* xb    = (unsigned short*)d_ws;                       // 32 MB
    unsigned short* wt    = xb + (size_t)NROWS * D_MODEL;                // 4 MB
    unsigned short* projb = wt + (size_t)NPROJ * D_MODEL;                // 64 MB

    k_cvt_x<<<(NROWS * D_MODEL) / (256 * 4), 256, 0, stream>>>(x, xb);
    k_cvt_w<<<dim3(NPROJ / 32, D_MODEL / 32), 256, 0, stream>>>(W, wt);
    k_gemm<<<(NPROJ / BN) * (NROWS / BM), 512, 0, stream>>>(xb, wt, bproj, projb);
    k_post<<<B_SZ * (T_LEN / CHUNK), 512, 0, stream>>>(projb, sinp, cosp, dwk, dwb, gamma, out);
}

// Round 5
// 152.063 us; speedup vs baseline: 1.0667x; 1.0667x over previous
//
#include <hip/hip_runtime.h>
#include <stdint.h>

#define D_MODEL 1024
#define T_LEN   4096
#define B_SZ    4
#define NROWS   (B_SZ * T_LEN)   // 16384
#define NPROJ   (2 * D_MODEL)    // 2048
#define CHUNK   16               // rows of T per k_post block

#define BM 256
#define BN 256
#define BK 64
#define NT (D_MODEL / BK)        // 16 K-steps

typedef __attribute__((ext_vector_type(8))) __bf16 bf16x8;
typedef __attribute__((ext_vector_type(4))) float  f32x4;

using as1_void = __attribute__((address_space(1))) void;
using as3_void = __attribute__((address_space(3))) void;

__device__ inline float bf2f(unsigned short u) {
    union { unsigned int i; float f; } v; v.i = ((unsigned int)u) << 16; return v.f;
}
__device__ inline unsigned short f2bf(float f) {
    union { float f; unsigned int i; } v; v.f = f;
    return (unsigned short)((v.i + 0x7fffu + ((v.i >> 16) & 1u)) >> 16);
}
__device__ inline float sigmoidf(float x) { return 1.0f / (1.0f + __expf(-x)); }

// ---------------- K0: fused converts (x fp32->bf16, W fp32->bf16 transposed) ----------------
__global__ __launch_bounds__(256) void k_cvt(const float* __restrict__ x,
                                             unsigned short* __restrict__ xb,
                                             const float* __restrict__ W,
                                             unsigned short* __restrict__ wt) {
    __shared__ unsigned short tile[32][33];
    int bid = blockIdx.x;
    if (bid < (NROWS * D_MODEL) / (256 * 4)) {
        int i = (bid * 256 + threadIdx.x) * 4;
        float4 v = *reinterpret_cast<const float4*>(x + i);
        ushort4 o;
        o.x = f2bf(v.x); o.y = f2bf(v.y); o.z = f2bf(v.z); o.w = f2bf(v.w);
        *reinterpret_cast<ushort4*>(xb + i) = o;
    } else {
        bid -= (NROWS * D_MODEL) / (256 * 4);
        int n0 = (bid & 63) * 32, k0 = (bid >> 6) * 32;
        int c = threadIdx.x & 31, r = threadIdx.x >> 5;  // r in 0..7
        #pragma unroll
        for (int i = 0; i < 4; i++) {
            int kk = r + i * 8;
            tile[kk][c] = f2bf(W[(uint64_t)(k0 + kk) * NPROJ + n0 + c]);
        }
        __syncthreads();
        #pragma unroll
        for (int i = 0; i < 4; i++) {
            int nn = r + i * 8;
            wt[(uint64_t)(n0 + nn) * D_MODEL + k0 + c] = tile[c][nn];
        }
    }
}

// ---------------- K1: GEMM proj = xb @ wt^T + bias, fused RoPE / sigmoid epilogue ----------------
// Body identical to the verified R3 kernel (85.6us, 0 bank conflicts).
// Epilogue: x_a tiles (n0<1024) store RoPE-rotated bf16 (pair partner via shfl_xor(v,1));
//           x_b tiles (n0>=1024) store sigmoid(proj) bf16 (gate precomputed).
__global__ __launch_bounds__(512, 2) void k_gemm(const unsigned short* __restrict__ xb,
                                                 const unsigned short* __restrict__ wt,
                                                 const float* __restrict__ bias,
                                                 const float* __restrict__ sinp,
                                                 const float* __restrict__ cosp,
                                                 unsigned short* __restrict__ projb) {
    __shared__ __align__(16) unsigned short As[2 * BM * BK];  // 64 KB
    __shared__ __align__(16) unsigned short Bs[2 * BM * BK];  // 64 KB

    const int tid  = threadIdx.x;
    const int lane = tid & 63;
    const int w    = tid >> 6;       // wave 0..7
    const int wm   = w >> 2;         // 0..1  (M half)
    const int wn   = w & 3;          // 0..3  (N quarter)

    // T1: 512 blocks = 8 n-tiles x 64 m-tiles; XCD k owns n-column k.
    const int bid = blockIdx.x;
    const int wg  = (bid & 7) * 64 + (bid >> 3);
    const int n0  = (wg >> 6) * BN;
    const int m0  = (wg & 63) * BM;

    const int srow = tid >> 3;                        // LDS row (mod 64) this thread fills
    const int scol = ((tid & 7) ^ (srow & 7)) * 8;    // T2: inverse-swizzled global col
    const int fr   = lane & 15;
    const int fq   = lane >> 4;

    f32x4 acc[8][4] = {};

    auto STAGE = [&](int buf, int ks) {
        #pragma unroll
        for (int i = 0; i < 4; ++i) {
            const unsigned short* ga = xb + (uint64_t)(m0 + i * 64 + srow) * D_MODEL + ks + scol;
            __builtin_amdgcn_global_load_lds((as1_void*)(void*)ga,
                (as3_void*)(void*)&As[buf * (BM * BK) + i * 4096 + w * 512], 16, 0, 0);
        }
        #pragma unroll
        for (int i = 0; i < 4; ++i) {
            const unsigned short* gb = wt + (uint64_t)(n0 + i * 64 + srow) * D_MODEL + ks + scol;
            __builtin_amdgcn_global_load_lds((as1_void*)(void*)gb,
                (as3_void*)(void*)&Bs[buf * (BM * BK) + i * 4096 + w * 512], 16, 0, 0);
        }
    };

    STAGE(0, 0);
    __syncthreads();

    for (int t = 0; t < NT; ++t) {
        const int cur = t & 1;
        if (t + 1 < NT) STAGE(1 - cur, (t + 1) * BK);   // issue-first prefetch

        const unsigned short* Ab = &As[cur * (BM * BK)];
        const unsigned short* Bb = &Bs[cur * (BM * BK)];
        #pragma unroll
        for (int kk = 0; kk < BK; kk += 32) {
            const int slot = (kk >> 3) + fq;            // global k-octet
            bf16x8 b[4];
            #pragma unroll
            for (int n = 0; n < 4; n++) {
                const int rb = wn * 64 + n * 16 + fr;
                b[n] = *reinterpret_cast<const bf16x8*>(&Bb[rb * 64 + ((slot ^ (fr & 7)) * 8)]);
            }
            #pragma unroll
            for (int m = 0; m < 8; m++) {
                const int ra = wm * 128 + m * 16 + fr;
                bf16x8 a = *reinterpret_cast<const bf16x8*>(&Ab[ra * 64 + ((slot ^ (fr & 7)) * 8)]);
                #pragma unroll
                for (int n = 0; n < 4; n++)
                    acc[m][n] = __builtin_amdgcn_mfma_f32_16x16x32_bf16(a, b[n], acc[m][n], 0, 0, 0);
            }
        }
        __syncthreads();
    }

    // epilogue: D layout col=lane&15, row=(lane>>4)*4+reg  [verified m89/m91]
    if (n0 < D_MODEL) {
        // x_a half: apply RoPE before storing. Pair (2k,2k+1) sits in adjacent
        // lanes (fr parity == gcol parity) -> partner value via shfl_xor(v,1).
        #pragma unroll
        for (int m = 0; m < 8; m++) {
            const int grow = m0 + wm * 128 + m * 16 + fq * 4;
            #pragma unroll
            for (int n = 0; n < 4; n++) {
                const int gcol = n0 + wn * 64 + n * 16 + fr;
                const float bv = bias[gcol];
                const int pidx = gcol >> 1;
                const bool evn = (gcol & 1) == 0;
                #pragma unroll
                for (int r = 0; r < 4; r++) {
                    const int trow = (grow + r) & (T_LEN - 1);
                    float v = acc[m][n][r] + bv;
                    float other = __shfl_xor(v, 1);
                    float cv = cosp[(uint64_t)trow * (D_MODEL / 2) + pidx];
                    float sv = sinp[(uint64_t)trow * (D_MODEL / 2) + pidx];
                    // even col: x1*c - x2*s ; odd col: x1*s + x2*c
                    float ro = evn ? (v * cv - other * sv) : (other * sv + v * cv);
                    projb[(uint64_t)(grow + r) * NPROJ + gcol] = f2bf(ro);
                }
            }
        }
    } else {
        // x_b half: store sigmoid(proj) -> gate is a plain multiply in k_post.
        #pragma unroll
        for (int m = 0; m < 8; m++) {
            const int grow = m0 + wm * 128 + m * 16 + fq * 4;
            #pragma unroll
            for (int n = 0; n < 4; n++) {
                const int gcol = n0 + wn * 64 + n * 16 + fr;
                const float bv = bias[gcol];
                #pragma unroll
                for (int r = 0; r < 4; r++) {
                    projb[(uint64_t)(grow + r) * NPROJ + gcol] = f2bf(sigmoidf(acc[m][n][r] + bv));
                }
            }
        }
    }
}

// ---------------- K2: conv7 + SiLU + gate + RMSNorm (inputs pre-rotated / pre-sigmoided) ----------------
__global__ __launch_bounds__(512) void k_post(const unsigned short* __restrict__ projb,
                                              const float* __restrict__ kw,
                                              const float* __restrict__ dwb,
                                              const float* __restrict__ gamma,
                                              float* __restrict__ out) {
    const int blk  = blockIdx.x;
    const int b    = blk / (T_LEN / CHUNK);
    const int t0   = (blk % (T_LEN / CHUNK)) * CHUNK;
    const int c    = threadIdx.x;          // channel-pair index 0..511
    const int d0   = c * 2;
    const uint64_t bbase = (uint64_t)b * T_LEN;

    float kwv[7][2];
    #pragma unroll
    for (int j = 0; j < 7; j++) {
        kwv[j][0] = kw[j * D_MODEL + d0];
        kwv[j][1] = kw[j * D_MODEL + d0 + 1];
    }
    const float bv0 = dwb[d0], bv1 = dwb[d0 + 1];
    const float gm0 = gamma[d0], gm1 = gamma[d0 + 1];

    __shared__ float red[2][8];

    auto load_row = [&](int tj, float& o0, float& o1) {
        if ((unsigned)tj < (unsigned)T_LEN) {
            ushort2 u = *reinterpret_cast<const ushort2*>(projb + (bbase + tj) * NPROJ + d0);
            o0 = bf2f(u.x); o1 = bf2f(u.y);
        } else { o0 = 0.f; o1 = 0.f; }
    };

    float rg[6][2];
    #pragma unroll
    for (int j = 0; j < 6; j++) load_row(t0 - 3 + j, rg[j][0], rg[j][1]);
    float nx0, nx1;
    load_row(t0 + 3, nx0, nx1);

    ushort2 xb_cur = *reinterpret_cast<const ushort2*>(projb + (bbase + t0) * NPROJ + D_MODEL + d0);

    for (int t = t0; t < t0 + CHUNK; ++t) {
        const float r60 = nx0, r61 = nx1;

        float acc0 = rg[0][0] * kwv[0][0] + rg[1][0] * kwv[1][0] + rg[2][0] * kwv[2][0]
                   + rg[3][0] * kwv[3][0] + rg[4][0] * kwv[4][0] + rg[5][0] * kwv[5][0]
                   + r60 * kwv[6][0] + bv0;
        float acc1 = rg[0][1] * kwv[0][1] + rg[1][1] * kwv[1][1] + rg[2][1] * kwv[2][1]
                   + rg[3][1] * kwv[3][1] + rg[4][1] * kwv[4][1] + rg[5][1] * kwv[5][1]
                   + r61 * kwv[6][1] + bv1;

        load_row(t + 4, nx0, nx1);
        const ushort2 xb_use = xb_cur;
        if (t + 1 < t0 + CHUNK) {
            xb_cur = *reinterpret_cast<const ushort2*>(projb + (bbase + t + 1) * NPROJ + D_MODEL + d0);
        }

        // SiLU(conv) * pre-sigmoided gate
        float a0 = acc0 * sigmoidf(acc0);
        float a1 = acc1 * sigmoidf(acc1);
        float g0 = a0 * bf2f(xb_use.x);
        float g1 = a1 * bf2f(xb_use.y);

        float ssq = g0 * g0 + g1 * g1;
        #pragma unroll
        for (int off = 32; off; off >>= 1) ssq += __shfl_down(ssq, off);
        const int p = t & 1;
        if ((threadIdx.x & 63) == 0) red[p][threadIdx.x >> 6] = ssq;
        __syncthreads();
        float total = red[p][0] + red[p][1] + red[p][2] + red[p][3]
                    + red[p][4] + red[p][5] + red[p][6] + red[p][7];
        const float inv = 1.0f / sqrtf(total * (1.0f / (float)D_MODEL) + 1e-8f);

        float2 o;
        o.x = g0 * inv * gm0;
        o.y = g1 * inv * gm1;
        *reinterpret_cast<float2*>(out + (bbase + t) * D_MODEL + d0) = o;

        #pragma unroll
        for (int j = 0; j < 5; j++) { rg[j][0] = rg[j + 1][0]; rg[j][1] = rg[j + 1][1]; }
        rg[5][0] = r60; rg[5][1] = r61;
    }
}

extern "C" void kernel_launch(void* const* d_in, const int* in_sizes, int n_in,
                              void* d_out, int out_size, void* d_ws, size_t ws_size,
                              hipStream_t stream) {
    const float* x     = (const float*)d_in[0];
    const float* sinp  = (const float*)d_in[1];
    const float* cosp  = (const float*)d_in[2];
    const float* W     = (const float*)d_in[3];
    const float* bproj = (const float*)d_in[4];
    const float* dwk   = (const float*)d_in[5];
    const float* dwb   = (const float*)d_in[6];
    const float* gamma = (const float*)d_in[7];
    float* out = (float*)d_out;

    unsigned short* xb    = (unsigned short*)d_ws;                       // 32 MB
    unsigned short* wt    = xb + (size_t)NROWS * D_MODEL;                // 4 MB
    unsigned short* projb = wt + (size_t)NPROJ * D_MODEL;                // 64 MB

    const int cvt_x_blocks = (NROWS * D_MODEL) / (256 * 4);              // 16384
    const int cvt_w_blocks = (NPROJ / 32) * (D_MODEL / 32);              // 2048
    k_cvt<<<cvt_x_blocks + cvt_w_blocks, 256, 0, stream>>>(x, xb, W, wt);
    k_gemm<<<(NPROJ / BN) * (NROWS / BM), 512, 0, stream>>>(xb, wt, bproj, sinp, cosp, projb);
    k_post<<<B_SZ * (T_LEN / CHUNK), 512, 0, stream>>>(projb, dwk, dwb, gamma, out);
}